// Round 1
// baseline (470.787 us; speedup 1.0000x reference)
//
#include <hip/hip_runtime.h>
#include <hip/hip_bf16.h>

#define D_MODEL 1024
#define NHEAD 16
#define DK 64
#define B_ 4
#define S_ 2048
#define ROWS (B_*S_)          // 8192
#define QKV_N (3*D_MODEL)     // 3072

typedef __attribute__((ext_vector_type(4))) float f32x4;
typedef __attribute__((ext_vector_type(8))) short bf16x8;
typedef unsigned short u16;
typedef unsigned int u32;

__device__ __forceinline__ u16 f2bf(float f) {
    union { float f; u32 u; } x; x.f = f;
    u32 r = x.u + 0x7fffu + ((x.u >> 16) & 1u);
    return (u16)(r >> 16);
}
__device__ __forceinline__ float bf2f(u16 h) {
    union { u32 u; float f; } x; x.u = ((u32)h) << 16;
    return x.f;
}

// async global->LDS, 16B per lane. LDS dest semantics: wave-uniform base + lane*16,
// so per-lane lds ptr MUST be base + lane*16 (ours is, by construction).
__device__ __forceinline__ void gload_lds16(const void* g, void* l) {
    __builtin_amdgcn_global_load_lds(
        (const __attribute__((address_space(1))) u32*)g,
        (__attribute__((address_space(3))) u32*)l, 16, 0, 0);
}

__global__ void cast_f32_bf16(const float* __restrict__ in, u16* __restrict__ out, int n) {
    int i = (blockIdx.x * blockDim.x + threadIdx.x) * 4;
    if (i + 3 < n) {
        float4 v = *(const float4*)(in + i);
        u16 o0 = f2bf(v.x), o1 = f2bf(v.y), o2 = f2bf(v.z), o3 = f2bf(v.w);
        ushort4 o; o.x = o0; o.y = o1; o.z = o2; o.w = o3;
        *(ushort4*)(out + i) = o;
    }
}

// C[m,n] = sum_k A[m,k] * B[n,k];  A:[M,K] bf16, B:[N,K] bf16 (both row-major)
// 128x128 tile, BK=32, 256 thr = 4 waves in 2x2, each wave 64x64 (4x4 MFMA frags)
template<int CT_BF16>
__global__ __launch_bounds__(256, 2)
void gemm_bt(const u16* __restrict__ A, const u16* __restrict__ Bm,
             void* __restrict__ Cp, int M, int N, int K) {
    __shared__ u16 As[128 * 32];
    __shared__ u16 Bs[128 * 32];
    const int tid = threadIdx.x;
    const int lane = tid & 63, wave = tid >> 6;
    const int m0 = blockIdx.y * 128, n0 = blockIdx.x * 128;
    const int wm = (wave >> 1) * 64, wn = (wave & 1) * 64;
    const int q4 = lane >> 4, c16 = lane & 15;
    f32x4 acc[4][4] = {};

    for (int k0 = 0; k0 < K; k0 += 32) {
        #pragma unroll
        for (int j = 0; j < 2; ++j) {
            int off = wave * 2048 + j * 1024 + lane * 16;  // bytes within 8KB tile
            int row = off >> 6, cb = off & 63;             // 64B per row (32 bf16)
            gload_lds16(A + (size_t)(m0 + row) * K + k0 + (cb >> 1), (char*)As + off);
            gload_lds16(Bm + (size_t)(n0 + row) * K + k0 + (cb >> 1), (char*)Bs + off);
        }
        __syncthreads();
        bf16x8 af[4], bf[4];
        #pragma unroll
        for (int mt = 0; mt < 4; ++mt)
            af[mt] = *(const bf16x8*)&As[(wm + mt * 16 + c16) * 32 + q4 * 8];
        #pragma unroll
        for (int nt = 0; nt < 4; ++nt)
            bf[nt] = *(const bf16x8*)&Bs[(wn + nt * 16 + c16) * 32 + q4 * 8];
        #pragma unroll
        for (int mt = 0; mt < 4; ++mt)
            #pragma unroll
            for (int nt = 0; nt < 4; ++nt)
                acc[mt][nt] = __builtin_amdgcn_mfma_f32_16x16x32_bf16(af[mt], bf[nt], acc[mt][nt], 0, 0, 0);
        __syncthreads();
    }
    #pragma unroll
    for (int mt = 0; mt < 4; ++mt)
        #pragma unroll
        for (int nt = 0; nt < 4; ++nt)
            #pragma unroll
            for (int r = 0; r < 4; ++r) {
                int row = m0 + wm + mt * 16 + q4 * 4 + r;
                int col = n0 + wn + nt * 16 + c16;
                float v = acc[mt][nt][r];
                if (CT_BF16) ((u16*)Cp)[(size_t)row * N + col] = f2bf(v);
                else         ((float*)Cp)[(size_t)row * N + col] = v;
            }
}

// RoPE in place on Q,K halves of QKV [8192, 3072] bf16. One thread per (row, pair).
__global__ void rope_kernel(u16* __restrict__ QKV, const int* __restrict__ pos) {
    int idx = blockIdx.x * blockDim.x + threadIdx.x;
    if (idx >= ROWS * 1024) return;
    int row = idx >> 10;
    int t = idx & 1023;
    int part = t >> 9;         // 0 = Q, 1 = K
    int p = t & 511;
    int h = p >> 5, i = p & 31;
    int col = part * D_MODEL + h * 64 + 2 * i;
    int s = row & (S_ - 1);
    // inv_freq = 10000^(-i/32) ; ln(10000)/32 = 0.2878231366242557
    float inv_freq = __expf(-(float)i * 0.2878231366242557f);
    float ang = (float)pos[s] * inv_freq;
    float sn, cs;
    sincosf(ang, &sn, &cs);
    u16* ptr = QKV + (size_t)row * QKV_N + col;
    float xe = bf2f(ptr[0]), xo = bf2f(ptr[1]);
    ptr[0] = f2bf(cs * xe - sn * xo);
    ptr[1] = f2bf(sn * xe + cs * xo);
}

// Flash attention. grid: x = q-tile (reversed for load balance), y = b*16+h.
// Block: 256 thr / 4 waves; Q tile = 64 rows; wave w owns rows [w*16, w*16+16).
__global__ __launch_bounds__(256, 2)
void attn_kernel(const u16* __restrict__ QKV, u16* __restrict__ O) {
    __shared__ u16 Kt[64 * 64];      // [key][d]
    __shared__ u16 Vt[64 * 72];      // [d][key], stride 72 (bank-shifted, 16B-aligned)
    __shared__ u16 Ps[4][16 * 72];   // per-wave P strip [qrow][key], stride 72
    const int tid = threadIdx.x, lane = tid & 63, wave = tid >> 6;
    const int q4 = lane >> 4, c16 = lane & 15;
    const int qt = gridDim.x - 1 - blockIdx.x;
    const int bh = blockIdx.y;
    const int b = bh >> 4, h = bh & 15;
    const size_t rowbase = (size_t)b * S_ * QKV_N;
    const int qb = qt * 64;

    // Q fragments (resident for the whole block): rows qb+wave*16+c16, k = q4*8 + 32*kk
    bf16x8 qf[2];
    {
        const u16* qptr = QKV + rowbase + (size_t)(qb + wave * 16 + c16) * QKV_N + h * 64 + q4 * 8;
        qf[0] = *(const bf16x8*)qptr;
        qf[1] = *(const bf16x8*)(qptr + 32);
    }
    f32x4 of[4] = {};             // O accum: col d = nt*16+c16, row = q4*4+r
    float m_i[4], l_i[4];
    #pragma unroll
    for (int r = 0; r < 4; ++r) { m_i[r] = -1e30f; l_i[r] = 0.f; }
    const int qrow0 = qb + wave * 16;

    for (int kt = 0; kt <= qt; ++kt) {
        // stage K tile [64 keys][64 d] via async copy (rows are 128B contiguous)
        #pragma unroll
        for (int j = 0; j < 2; ++j) {
            int off = wave * 2048 + j * 1024 + lane * 16;
            int row = off >> 7, cb = off & 127;
            gload_lds16(QKV + rowbase + (size_t)(kt * 64 + row) * QKV_N + D_MODEL + h * 64 + (cb >> 1),
                        (char*)Kt + off);
        }
        // stage V transposed: lane -> key=lane, d = wave*16 + i  (conflict-free writes)
        {
            const u16* vptr = QKV + rowbase + (size_t)(kt * 64 + lane) * QKV_N + 2 * D_MODEL + h * 64 + wave * 16;
            bf16x8 v0 = *(const bf16x8*)vptr;
            bf16x8 v1 = *(const bf16x8*)(vptr + 8);
            #pragma unroll
            for (int i = 0; i < 8; ++i) Vt[(wave * 16 + i) * 72 + lane] = (u16)v0[i];
            #pragma unroll
            for (int i = 0; i < 8; ++i) Vt[(wave * 16 + 8 + i) * 72 + lane] = (u16)v1[i];
        }
        __syncthreads();

        // S = Q K^T : wave's 16 q-rows x 64 keys, 4 C-frags (nt = key sub-tile)
        f32x4 sf[4] = {};
        #pragma unroll
        for (int kk = 0; kk < 2; ++kk)
            #pragma unroll
            for (int nt = 0; nt < 4; ++nt) {
                bf16x8 kf = *(const bf16x8*)&Kt[(nt * 16 + c16) * 64 + kk * 32 + q4 * 8];
                sf[nt] = __builtin_amdgcn_mfma_f32_16x16x32_bf16(qf[kk], kf, sf[nt], 0, 0, 0);
            }

        // online softmax (per q-row r: row = q4*4+r; row spread over 16 lanes of the quad)
        const bool diag = (kt == qt);
        float alpha[4];
        #pragma unroll
        for (int r = 0; r < 4; ++r) {
            int qg = qrow0 + q4 * 4 + r;
            float sv[4], mx = -1e30f;
            #pragma unroll
            for (int nt = 0; nt < 4; ++nt) {
                float s = sf[nt][r] * 0.125f;
                int kg = kt * 64 + nt * 16 + c16;
                if (diag && kg > qg) s = -1e30f;
                sv[nt] = s;
                mx = fmaxf(mx, s);
            }
            #pragma unroll
            for (int d = 1; d < 16; d <<= 1) mx = fmaxf(mx, __shfl_xor(mx, d, 64));
            float mnew = fmaxf(m_i[r], mx);
            float a = __expf(m_i[r] - mnew);
            float rs = 0.f;
            #pragma unroll
            for (int nt = 0; nt < 4; ++nt) {
                float pv = __expf(sv[nt] - mnew);
                rs += pv;
                Ps[wave][(q4 * 4 + r) * 72 + nt * 16 + c16] = f2bf(pv);
            }
            #pragma unroll
            for (int d = 1; d < 16; d <<= 1) rs += __shfl_xor(rs, d, 64);
            l_i[r] = l_i[r] * a + rs;
            m_i[r] = mnew;
            alpha[r] = a;
        }
        #pragma unroll
        for (int nt = 0; nt < 4; ++nt)
            #pragma unroll
            for (int r = 0; r < 4; ++r)
                of[nt][r] *= alpha[r];

        // O += P V : A = P strip (A-layout from LDS), B = Vt
        #pragma unroll
        for (int kk = 0; kk < 2; ++kk) {
            bf16x8 pf = *(const bf16x8*)&Ps[wave][c16 * 72 + kk * 32 + q4 * 8];
            #pragma unroll
            for (int nt = 0; nt < 4; ++nt) {
                bf16x8 vf = *(const bf16x8*)&Vt[(nt * 16 + c16) * 72 + kk * 32 + q4 * 8];
                of[nt] = __builtin_amdgcn_mfma_f32_16x16x32_bf16(pf, vf, of[nt], 0, 0, 0);
            }
        }
        __syncthreads();
    }

    // write O [8192, 1024] bf16, col = h*64 + nt*16 + c16
    #pragma unroll
    for (int r = 0; r < 4; ++r) {
        float inv = 1.0f / l_i[r];
        int row = b * S_ + qb + wave * 16 + q4 * 4 + r;
        #pragma unroll
        for (int nt = 0; nt < 4; ++nt)
            O[(size_t)row * D_MODEL + h * 64 + nt * 16 + c16] = f2bf(of[nt][r] * inv);
    }
}

extern "C" void kernel_launch(void* const* d_in, const int* in_sizes, int n_in,
                              void* d_out, int out_size, void* d_ws, size_t ws_size,
                              hipStream_t stream) {
    const float* x  = (const float*)d_in[0];
    const int*   tp = (const int*)d_in[1];
    const float* Wq = (const float*)d_in[2];
    const float* Wk = (const float*)d_in[3];
    const float* Wv = (const float*)d_in[4];
    const float* Wo = (const float*)d_in[5];
    float* out = (float*)d_out;

    char* ws = (char*)d_ws;
    u16* xb    = (u16*)(ws);                 // 16,777,216 B
    u16* Wqkvb = (u16*)(ws + 16777216);      //  6,291,456 B
    u16* Wob   = (u16*)(ws + 23068672);      //  2,097,152 B
    u16* QKV   = (u16*)(ws + 25165824);      // 50,331,648 B
    u16* Ob    = (u16*)(ws + 75497472);      // 16,777,216 B  (total 92,274,688 B)

    cast_f32_bf16<<<dim3(8192), dim3(256), 0, stream>>>(x, xb, ROWS * D_MODEL);
    cast_f32_bf16<<<dim3(1024), dim3(256), 0, stream>>>(Wq, Wqkvb, D_MODEL * D_MODEL);
    cast_f32_bf16<<<dim3(1024), dim3(256), 0, stream>>>(Wk, Wqkvb + D_MODEL * D_MODEL, D_MODEL * D_MODEL);
    cast_f32_bf16<<<dim3(1024), dim3(256), 0, stream>>>(Wv, Wqkvb + 2 * D_MODEL * D_MODEL, D_MODEL * D_MODEL);
    cast_f32_bf16<<<dim3(1024), dim3(256), 0, stream>>>(Wo, Wob, D_MODEL * D_MODEL);

    gemm_bt<1><<<dim3(QKV_N / 128, ROWS / 128), dim3(256), 0, stream>>>(
        xb, Wqkvb, (void*)QKV, ROWS, QKV_N, D_MODEL);

    rope_kernel<<<dim3(ROWS * 1024 / 256), dim3(256), 0, stream>>>(QKV, tp);

    attn_kernel<<<dim3(S_ / 64, B_ * NHEAD), dim3(256), 0, stream>>>(QKV, Ob);

    gemm_bt<0><<<dim3(D_MODEL / 128, ROWS / 128), dim3(256), 0, stream>>>(
        Ob, Wob, (void*)out, ROWS, D_MODEL, D_MODEL);
}